// Round 7
// baseline (902.557 us; speedup 1.0000x reference)
//
#include <hip/hip_runtime.h>
#include <stdint.h>

// Problem constants: B=4, S=2048, E=2048, H=16, HD=128
// Dtypes: inputs f32; OUTPUT f32. Intermediates bf16 (2% threshold).
#define BB 4
#define SS 2048
#define EE 2048
#define HH 16
#define HD 128
// SCALE * log2(e): folded into Q at the projection epilogue so attention
// softmax is pure exp2 (saves a v_mul per score element).
#define QSCALE 0.1275174490044696f

typedef __attribute__((ext_vector_type(8))) short bf16x8;
typedef __attribute__((ext_vector_type(4))) float f32x4;

__device__ __forceinline__ unsigned short f2bf(float f) {
  union { float f; unsigned u; } v;
  v.f = f;
  unsigned r = (v.u + 0x7fffu + ((v.u >> 16) & 1u)) >> 16;
  return (unsigned short)r;
}

// async global->LDS, 16B per lane. LDS dest = wave-uniform base + lane*16.
__device__ __forceinline__ void lds16(const void* g, void* l) {
  __builtin_amdgcn_global_load_lds(
      (__attribute__((address_space(1))) void*)(uintptr_t)g,
      (__attribute__((address_space(3))) void*)(uintptr_t)l,
      16, 0, 0);
}

// ---------------- fp32 -> bf16 conversion ----------------
__global__ void cvt_f32_bf16(const float* __restrict__ src,
                             unsigned short* __restrict__ dst, int n4) {
  int i = blockIdx.x * blockDim.x + threadIdx.x;
  if (i >= n4) return;
  float4 v = ((const float4*)src)[i];
  ushort4 o;
  o.x = f2bf(v.x); o.y = f2bf(v.y); o.z = f2bf(v.z); o.w = f2bf(v.w);
  ((ushort4*)dst)[i] = o;
}

// 3 weight matrices in one launch (blockIdx.y selects).
__global__ void cvt_w3(const float* __restrict__ Wq,
                       const float* __restrict__ Wk,
                       const float* __restrict__ Wv,
                       unsigned short* __restrict__ dst, int n4each) {
  const int which = blockIdx.y;
  const float* src = (which == 0) ? Wq : (which == 1) ? Wk : Wv;
  unsigned short* d = dst + (size_t)which * 4194304;
  int i = blockIdx.x * blockDim.x + threadIdx.x;
  if (i >= n4each) return;
  float4 v = ((const float4*)src)[i];
  ushort4 o;
  o.x = f2bf(v.x); o.y = f2bf(v.y); o.z = f2bf(v.z); o.w = f2bf(v.w);
  ((ushort4*)d)[i] = o;
}

// ---------------- 256x256 8-phase bt-GEMM core (m201 template) -----------
// (unchanged from r5/r6 -- passed)
__device__ __forceinline__ void gemm256_core(
    const unsigned short* __restrict__ A,
    const unsigned short* __restrict__ Bm,
    char* lds, int m0, int n0, f32x4 acc[8][4]) {
  const int t = threadIdx.x;
  const int w = t >> 6;
  const int ln = t & 63;
  const int lr = ln & 15;
  const int lg = ln >> 4;
  const int wr = w >> 2;   // 0..1: M half
  const int wc = w & 3;    // 0..3: N quarter

  unsigned offs[4][2];
  int dof[4][2];  // wave-uniform LDS byte offset within buffer
#pragma unroll
  for (int h = 0; h < 2; ++h)
#pragma unroll
    for (int s = 0; s < 2; ++s) {
      const int C = s * 512 + w * 64 + ln;
      const int row = C >> 3;
      const int kch = (C & 7) ^ (row & 7);
      offs[h][s]     = (unsigned)(m0 + h * 128 + row) * EE + kch * 8;
      offs[2 + h][s] = (unsigned)(n0 + h * 128 + row) * EE + kch * 8;
      dof[h][s] = h * 16384 + (s * 512 + w * 64) * 16;
      dof[2 + h][s] = 32768 + h * 16384 + (s * 512 + w * 64) * 16;
    }

#pragma unroll
  for (int i = 0; i < 8; ++i)
#pragma unroll
    for (int j = 0; j < 4; ++j) acc[i][j] = (f32x4){0.f, 0.f, 0.f, 0.f};

#pragma unroll
  for (int q = 0; q < 4; ++q)
#pragma unroll
    for (int s = 0; s < 2; ++s)
      lds16(((q < 2) ? A : Bm) + offs[q][s], lds + dof[q][s]);
  __syncthreads();

  const int cc0 = lg ^ (lr & 7);        // ks=0
  const int cc1 = (4 + lg) ^ (lr & 7);  // ks=1
  const int brbase = (wc & 1) * 64;

  bf16x8 afr[4][2];
  bf16x8 bfr[2][2][2];
  int bufo = 0;
  for (int kt = 0; kt < EE; kt += 64) {
    char* cb = lds + bufo;
    char* pb = lds + (bufo ^ 65536);
    const char* Ard = cb + wr * 16384;
    const char* Brd = cb + 32768 + (wc >> 1) * 16384;
    const bool pre = (kt + 64 < EE);
#pragma unroll
    for (int ph = 0; ph < 4; ++ph) {
      const int qm = ph >> 1, qn = ph & 1;
      if (qn == 0) {
#pragma unroll
        for (int i = 0; i < 4; ++i) {
          const int r = qm * 64 + i * 16 + lr;
          afr[i][0] = *(const bf16x8*)(Ard + r * 128 + cc0 * 16);
          afr[i][1] = *(const bf16x8*)(Ard + r * 128 + cc1 * 16);
        }
      }
      if (ph < 2) {
#pragma unroll
        for (int j = 0; j < 2; ++j) {
          const int r = brbase + ph * 32 + j * 16 + lr;
          bfr[ph][j][0] = *(const bf16x8*)(Brd + r * 128 + cc0 * 16);
          bfr[ph][j][1] = *(const bf16x8*)(Brd + r * 128 + cc1 * 16);
        }
      }
      if (pre) {
        lds16(((ph < 2) ? A : Bm) + (offs[ph][0] + (kt + 64)), pb + dof[ph][0]);
        lds16(((ph < 2) ? A : Bm) + (offs[ph][1] + (kt + 64)), pb + dof[ph][1]);
      }
      __builtin_amdgcn_s_barrier();
      __builtin_amdgcn_s_setprio(1);
#pragma unroll
      for (int i = 0; i < 4; ++i)
#pragma unroll
        for (int j = 0; j < 2; ++j) {
          acc[qm * 4 + i][qn * 2 + j] = __builtin_amdgcn_mfma_f32_16x16x32_bf16(
              afr[i][0], bfr[qn][j][0], acc[qm * 4 + i][qn * 2 + j], 0, 0, 0);
          acc[qm * 4 + i][qn * 2 + j] = __builtin_amdgcn_mfma_f32_16x16x32_bf16(
              afr[i][1], bfr[qn][j][1], acc[qm * 4 + i][qn * 2 + j], 0, 0, 0);
        }
      __builtin_amdgcn_s_setprio(0);
      if (ph < 3) {
        __builtin_amdgcn_s_barrier();  // intra-tile: buffers stable
      } else {
        __syncthreads();  // tile boundary: fence + vmcnt(0) drain + barrier
      }
    }
    bufo ^= 65536;
  }
}

// ---------------- fused QKV projection (256^2 tiles) ----------------
__global__ __launch_bounds__(512, 1)
void gemm_qkv(const unsigned short* __restrict__ X,
              const unsigned short* __restrict__ W,
              const float* __restrict__ bq,
              const float* __restrict__ bk,
              const float* __restrict__ bv,
              unsigned short* __restrict__ Qb,
              unsigned short* __restrict__ Kb,
              unsigned short* __restrict__ Vb) {
  __shared__ __align__(16) char lds[131072];
  const int m0 = blockIdx.y * 256;
  const int n0 = blockIdx.x * 256;
  f32x4 acc[8][4];
  gemm256_core(X, W, lds, m0, n0, acc);

  const int t = threadIdx.x;
  const int w = t >> 6;
  const int lr = t & 15;
  const int lg = (t & 63) >> 4;
  const int wrm = (w >> 2) * 128;
  const int wcn = (w & 3) * 64;

  const int region = n0 >> 11;  // 0=Q 1=K 2=V
  unsigned short* Dst = (region == 0) ? Qb : (region == 1) ? Kb : Vb;
  const float* bp = (region == 0) ? bq : (region == 1) ? bk : bv;

  if (region == 2) {
#pragma unroll
    for (int mi = 0; mi < 8; ++mi) {
      const int row0 = m0 + wrm + mi * 16 + lg * 4;
      const int b = row0 >> 11;
      const int s = row0 & 2047;
#pragma unroll
      for (int nj = 0; nj < 4; ++nj) {
        const int c = (n0 + wcn + nj * 16 + lr) & 2047;
        const float bias = bp[c];
        const int h = c >> 7, hd = c & 127;
        const size_t base = ((size_t)(b * HH + h) * HD + hd) * SS + s;
#pragma unroll
        for (int re = 0; re < 4; ++re)
          Dst[base + re] = f2bf(acc[mi][nj][re] + bias);
      }
    }
  } else {
    const float osc = (region == 0) ? QSCALE : 1.0f;
#pragma unroll
    for (int mi = 0; mi < 8; ++mi) {
      const int row0 = m0 + wrm + mi * 16 + lg * 4;
      const int b = row0 >> 11;
      const int s = row0 & 2047;
#pragma unroll
      for (int nj = 0; nj < 4; ++nj) {
        const int c = (n0 + wcn + nj * 16 + lr) & 2047;
        const float bias = bp[c];
        const int h = c >> 7, hd = c & 127;
        const size_t base = ((size_t)(b * HH + h) * SS + s) * HD + hd;
#pragma unroll
        for (int re = 0; re < 4; ++re)
          Dst[base + (size_t)re * HD] = f2bf((acc[mi][nj][re] + bias) * osc);
      }
    }
  }
}

// ---------------- output projection (256^2 tiles, f32 output!) -----------
__global__ __launch_bounds__(512, 1)
void gemm_out(const unsigned short* __restrict__ A,
              const unsigned short* __restrict__ W,
              const float* __restrict__ bo,
              float* __restrict__ Out) {
  __shared__ __align__(16) char lds[131072];
  const int m0 = blockIdx.y * 256;
  const int n0 = blockIdx.x * 256;
  f32x4 acc[8][4];
  gemm256_core(A, W, lds, m0, n0, acc);

  const int t = threadIdx.x;
  const int w = t >> 6;
  const int lr = t & 15;
  const int lg = (t & 63) >> 4;
  const int wrm = (w >> 2) * 128;
  const int wcn = (w & 3) * 64;

#pragma unroll
  for (int mi = 0; mi < 8; ++mi) {
    const int row0 = m0 + wrm + mi * 16 + lg * 4;
#pragma unroll
    for (int nj = 0; nj < 4; ++nj) {
      const int col = n0 + wcn + nj * 16 + lr;
      const float bias = bo[col];
#pragma unroll
      for (int re = 0; re < 4; ++re)
        Out[(size_t)(row0 + re) * EE + col] = acc[mi][nj][re] + bias;
    }
  }
}

// ---------------- MFMA flash attention (v4: 8-wave blocks) ----------------
// v4 vs v3: SAME per-wave math; blocks are now 8 waves (512 thr) sharing the
// same 64 KiB K/V double-buffer. Rationale (r6 counters): occupancy was
// LDS-limited at 2 blocks/CU x 4 waves = 8 waves/CU (21%) while VGPR=92
// permits 4 waves/SIMD. 8-wave blocks at 64 KiB -> 2 blocks/CU = 16
// waves/CU (~42%): doubles cross-wave MFMA/VALU overlap (the per-wave
// softmax VALU — 32 exp2 + fmax/cvt chains — is irreducible and must be
// hidden under other waves' MFMA). Staging per wave halves (1024 chunks /
// 8 waves). __launch_bounds__(512,4) pins the <=128-VGPR budget.
__global__ __launch_bounds__(512, 4)
void attn_mfma(const unsigned short* __restrict__ Qb,
               const unsigned short* __restrict__ Kb,
               const unsigned short* __restrict__ Vtb,
               unsigned short* __restrict__ At) {
  // [0,32K) buf0 {K 16K, Vt 16K}; [32K,64K) buf1
  __shared__ __align__(16) char lds[65536];
  const int t = threadIdx.x;
  const int w = t >> 6;
  const int ln = t & 63;
  const int lr = ln & 15;
  const int lg = ln >> 4;
  const int la = lg >> 1;      // lane-group high bit
  const int lb = lg & 1;       // lane-group low bit
  const bool sela = (la == 0);
  const bool abeq = (la == lb);
  const bool b0eq = (lb == 0);

  const int bh = blockIdx.y;
  const int qw = blockIdx.x * 256 + w * 32;  // wave's q base within head

  const unsigned short* Qh = Qb + (size_t)bh * SS * HD;
  const unsigned short* Kh = Kb + (size_t)bh * SS * HD;
  const unsigned short* Vh = Vtb + (size_t)bh * HD * SS;  // [d][s]

  // Q fragments (B-operand): q = qw + qi*16 + lr, d = ds*32 + lg*8 + 0..7
  bf16x8 qfr[2][4];
#pragma unroll
  for (int qi = 0; qi < 2; ++qi)
#pragma unroll
    for (int ds = 0; ds < 4; ++ds)
      qfr[qi][ds] = *(const bf16x8*)(Qh + (size_t)(qw + qi * 16 + lr) * HD + ds * 32 + lg * 8);

  // O^T accumulator: acc[df][qi] holds O[q = qi*16+lr][d = df*16 + 4*lg + re]
  f32x4 acc[8][2];
#pragma unroll
  for (int df = 0; df < 8; ++df)
#pragma unroll
    for (int qi = 0; qi < 2; ++qi)
      acc[df][qi] = (f32x4){0.f, 0.f, 0.f, 0.f};
  float mrun[2] = {-3.0e38f, -3.0e38f};
  float lsum[2] = {0.f, 0.f};

  // Hoisted staging pointers (XOR pre-swizzled global sources; LDS linear).
  // 1024 chunks over 8 waves: chunk c = i*512 + w*64 + ln, i<2.
  // K chunk c: row=c>>4, gch=(c&15)^(row&7). V chunk c: d=c>>3, kc=(c&7)^(d&7).
  const unsigned short* gk[2];
  const unsigned short* gv[2];
  int ldk[2], ldv[2];
#pragma unroll
  for (int i = 0; i < 2; ++i) {
    const int c = i * 512 + w * 64 + ln;
    const int row = c >> 4;
    const int gch = (c & 15) ^ (row & 7);
    gk[i] = Kh + (size_t)row * HD + gch * 8;
    const int d = c >> 3;
    const int kc = (c & 7) ^ (d & 7);
    gv[i] = Vh + (size_t)d * SS + kc * 8;
    ldk[i] = (i * 512 + w * 64) * 16;
    ldv[i] = 16384 + (i * 512 + w * 64) * 16;
  }

#define STAGE_KV(bufbase)                                                      \
  do {                                                                         \
    _Pragma("unroll") for (int i = 0; i < 2; ++i) {                            \
      lds16(gk[i], (bufbase) + ldk[i]);                                        \
      lds16(gv[i], (bufbase) + ldv[i]);                                        \
    }                                                                          \
    _Pragma("unroll") for (int i = 0; i < 2; ++i) {                            \
      gk[i] += 64 * HD;                                                        \
      gv[i] += 64;                                                             \
    }                                                                          \
  } while (0)

  STAGE_KV(lds);
  __syncthreads();  // implicit vmcnt(0): tile 0 landed

  int cur = 0;
  for (int kt = 0; kt < SS; kt += 64) {
    if (kt + 64 < SS) STAGE_KV(lds + ((cur ^ 1) * 32768));

    char* Ks = lds + cur * 32768;
    char* Vs = Ks + 16384;

    // --- QK^T (swapped): St[k = kf*16 + 4*lg + re][q = qi*16 + lr]
    f32x4 st[4][2];
    __builtin_amdgcn_s_setprio(1);
#pragma unroll
    for (int kf = 0; kf < 4; ++kf) {
#pragma unroll
      for (int qi = 0; qi < 2; ++qi) st[kf][qi] = (f32x4){0.f, 0.f, 0.f, 0.f};
#pragma unroll
      for (int ds = 0; ds < 4; ++ds) {
        const int krow = kf * 16 + lr;
        bf16x8 kfr = *(const bf16x8*)(Ks + krow * 256 + (((ds * 4 + lg) ^ (krow & 7)) * 16));
#pragma unroll
        for (int qi = 0; qi < 2; ++qi)
          st[kf][qi] = __builtin_amdgcn_mfma_f32_16x16x32_bf16(kfr, qfr[qi][ds], st[kf][qi], 0, 0, 0);
      }
    }
    __builtin_amdgcn_s_setprio(0);

    // --- online softmax + in-register P->bf16 handoff
    bf16x8 pf[2][2];  // [ks][qi] PV B-operand fragments
#pragma unroll
    for (int qi = 0; qi < 2; ++qi) {
      float tm = st[0][qi][0];
#pragma unroll
      for (int kf = 0; kf < 4; ++kf)
#pragma unroll
        for (int r = 0; r < 4; ++r) tm = fmaxf(tm, st[kf][qi][r]);
      tm = fmaxf(tm, __shfl_xor(tm, 16, 64));
      tm = fmaxf(tm, __shfl_xor(tm, 32, 64));
      if (!__all(tm <= mrun[qi] + 8.0f)) {
        const float mnew = fmaxf(mrun[qi], tm);
        const float alpha = __builtin_exp2f(mrun[qi] - mnew);
        mrun[qi] = mnew;
        lsum[qi] *= alpha;
#pragma unroll
        for (int df = 0; df < 8; ++df) {
          acc[df][qi][0] *= alpha; acc[df][qi][1] *= alpha;
          acc[df][qi][2] *= alpha; acc[df][qi][3] *= alpha;
        }
      }
      const float mcur = mrun[qi];
      float rs = 0.f;
      // cells: cell[kf][i] = pack(p[2i], p[2i+1]); k = kf*16 + 4*lg + 2i+b0
      unsigned cell[4][2];
#pragma unroll
      for (int kf = 0; kf < 4; ++kf) {
        const float p0 = __builtin_exp2f(st[kf][qi][0] - mcur);
        const float p1 = __builtin_exp2f(st[kf][qi][1] - mcur);
        const float p2 = __builtin_exp2f(st[kf][qi][2] - mcur);
        const float p3 = __builtin_exp2f(st[kf][qi][3] - mcur);
        rs += (p0 + p1) + (p2 + p3);
        asm("v_cvt_pk_bf16_f32 %0, %1, %2" : "=v"(cell[kf][0]) : "v"(p0), "v"(p1));
        asm("v_cvt_pk_bf16_f32 %0, %1, %2" : "=v"(cell[kf][1]) : "v"(p2), "v"(p3));
      }
      lsum[qi] += rs;

      // Butterfly round 1 (xor32, flips la): keep kf&1==la halves.
      unsigned own1[2][2], rcv1[2][2];
#pragma unroll
      for (int j = 0; j < 2; ++j)
#pragma unroll
        for (int i = 0; i < 2; ++i) {
          const unsigned snd = sela ? cell[2 * j + 1][i] : cell[2 * j][i];
          rcv1[j][i] = (unsigned)__shfl_xor((int)snd, 32, 64);
          own1[j][i] = sela ? cell[2 * j][i] : cell[2 * j + 1][i];
        }
      // Round 2 (xor16, flips lb): keep a_src==lb.
      unsigned kp[2][2], rr[2][2];
#pragma unroll
      for (int j = 0; j < 2; ++j)
#pragma unroll
        for (int i = 0; i < 2; ++i) {
          const unsigned s2 = abeq ? rcv1[j][i] : own1[j][i];
          rr[j][i] = (unsigned)__shfl_xor((int)s2, 16, 64);
          kp[j][i] = abeq ? own1[j][i] : rcv1[j][i];
        }
      // Assemble B-frags: word m/2: F[sb][i], sb = m>>2, F[sb]=(sb==lb)?kp:rr
#pragma unroll
      for (int ks = 0; ks < 2; ++ks) {
        union { unsigned u[4]; bf16x8 v; } pk;
        pk.u[0] = b0eq ? kp[ks][0] : rr[ks][0];
        pk.u[1] = b0eq ? kp[ks][1] : rr[ks][1];
        pk.u[2] = b0eq ? rr[ks][0] : kp[ks][0];
        pk.u[3] = b0eq ? rr[ks][1] : kp[ks][1];
        pf[ks][qi] = pk.v;
      }
    }

    // --- PV: O^T[d][q] += Vt x P (P fragments in registers)
    __builtin_amdgcn_s_setprio(1);
#pragma unroll
    for (int df = 0; df < 8; ++df) {
#pragma unroll
      for (int ks = 0; ks < 2; ++ks) {
        const int drow = df * 16 + lr;
        bf16x8 vfr = *(const bf16x8*)(Vs + drow * 128 + (((ks * 4 + lg) ^ (drow & 7)) * 16));
#pragma unroll
        for (int qi = 0; qi < 2; ++qi)
          acc[df][qi] = __builtin_amdgcn_mfma_f32_16x16x32_bf16(vfr, pf[ks][qi], acc[df][qi], 0, 0, 0);
      }
    }
    __builtin_amdgcn_s_setprio(0);

    __syncthreads();
    cur ^= 1;
  }

  // --- finalize: cross-lane l reduce, divide, store bf16
  const int b = bh >> 4, h = bh & 15;
#pragma unroll
  for (int qi = 0; qi < 2; ++qi) {
    float l = lsum[qi];
    l += __shfl_xor(l, 16, 64);
    l += __shfl_xor(l, 32, 64);
    const float rl = 1.0f / l;
    const int s = qw + qi * 16 + lr;
    unsigned short* orow = At + ((size_t)(b * SS + s)) * EE + h * HD;
#pragma unroll
    for (int df = 0; df < 8; ++df)
#pragma unroll
      for (int r = 0; r < 4; ++r)
        orow[df * 16 + lg * 4 + r] = f2bf(acc[df][qi][r] * rl);
  }
}

// ---------------- launcher ----------------
extern "C" void kernel_launch(void* const* d_in, const int* in_sizes, int n_in,
                              void* d_out, int out_size, void* d_ws, size_t ws_size,
                              hipStream_t stream) {
  const float* QKV = (const float*)d_in[0];
  const float* Wq  = (const float*)d_in[1];
  const float* bq  = (const float*)d_in[2];
  const float* Wk  = (const float*)d_in[3];
  const float* bk  = (const float*)d_in[4];
  const float* Wv  = (const float*)d_in[5];
  const float* bv  = (const float*)d_in[6];
  const float* Wo  = (const float*)d_in[7];
  const float* bo  = (const float*)d_in[8];
  // d_in[9] = is_causal: masking is a no-op in the reference

  unsigned short* Xb = (unsigned short*)d_out;  // dead before gemm_out writes

  char* ws = (char*)d_ws;  // 152 MiB
  unsigned short* Wqkvb = (unsigned short*)(ws);                 // [  0, 24M)
  unsigned short* Qb    = (unsigned short*)(ws + ( 24u << 20));  // [ 24, 56M)
  unsigned short* Kb    = (unsigned short*)(ws + ( 56u << 20));  // [ 56, 88M)
  unsigned short* Vb    = (unsigned short*)(ws + ( 88u << 20));  // [ 88,120M) (transposed [b,h,d,s])
  unsigned short* At    = (unsigned short*)(ws + (120u << 20));  // [120,152M)
  unsigned short* Wob   = Wqkvb;  // reuses dead Wqkv region

  cvt_f32_bf16<<<dim3(16384), dim3(256), 0, stream>>>(QKV, Xb, 4194304);
  cvt_w3<<<dim3(4096, 3), dim3(256), 0, stream>>>(Wq, Wk, Wv, Wqkvb, 1048576);

  gemm_qkv<<<dim3(24, 32), dim3(512), 0, stream>>>(Xb, Wqkvb, bq, bk, bv, Qb, Kb, Vb);
  attn_mfma<<<dim3(8, 64), dim3(512), 0, stream>>>(Qb, Kb, Vb, At);

  cvt_f32_bf16<<<dim3(4096), dim3(256), 0, stream>>>(Wo, Wob, 1048576);
  gemm_out<<<dim3(8, 32), dim3(512), 0, stream>>>(At, Wob, bo, (float*)d_out);
}